// Round 12
// baseline (205.969 us; speedup 1.0000x reference)
//
#include <hip/hip_runtime.h>
#include <hip/hip_bf16.h>

// WeisfeilerLehman: labels0 = argmax(x, -1); 3x ordered polynomial hash over edges.
// All arithmetic mod 2^32 (uint32 wrap) == reference int64 truncated to int32.
// R22/R23: prefix-path restructure (k_btot + k_prep replace scan+transp);
//      hist never rewritten. Measured 195.7us.
// R24: k_btot folded into k_hist_argmax -- hist blocks atomicAdd their LDS
//      per-bucket counts into btot at write-out (512 adds/address, L2-trivial).
//      btot zero-init via 3KB hipMemsetAsync (graph-safe, overlaps launch
//      pipeline). One fewer dispatch + one fewer serial dependency link.

#define WL_D 128
#define NCH 512             // MSD chunk count (scatter grid)
#define GRID_F 2048         // fused hist/argmax grid
#define BT 512              // threads per block (8 waves)
#define MSDW 8
#define BBITS 7             // bucket = row >> 7
#define BROWS 128           // rows per bucket
#define NBK 1024            // max buckets (N <= 131072)
#define RLSHIFT 23          // buf pack: (rl << 23) | col   (col < 2^23)
#define COLMASK ((1u << RLSHIFT) - 1u)
#define CMAX 5120           // LDS-staged output cap (20 KB)
#define NBMAX 13            // unrolled batches per wave in k_scatter (chunk 6250)
#define KBMAX 10            // unrolled batches per wave in k_bucket (len <= CMAX)
#define HP8 2487512833u     // 31^8 mod 2^32

// XCD-chunked chunk assignment: blockIdx -> chunk such that each XCD (bid % 8
// under round-robin dispatch) owns NCH/8 consecutive chunks. Bijective on [0,NCH).
__device__ inline int xcd_chunk(int bid) { return ((bid & 7) << 6) | (bid >> 3); }

// mask of lanes whose low BITS bits of v match mine (inactive lanes use a
// sentinel outside the valid key range so they never match active lanes)
template <int BITS>
__device__ inline unsigned long long match_key(unsigned v) {
    unsigned long long m = ~0ull;
    #pragma unroll
    for (int b = 0; b < BITS; ++b) {
        unsigned long long s = __ballot((v >> b) & 1u);
        m &= ((v >> b) & 1u) ? s : ~s;
    }
    return m;
}

// ---- fused: chunk bucket-histogram + btot atomics (blocks < NCH) OR argmax ----
__global__ void __launch_bounds__(BT)
k_hist_argmax(const float* __restrict__ x, const int* __restrict__ ei,
              unsigned* __restrict__ lab0, unsigned* __restrict__ hist,
              unsigned* __restrict__ btot, int N, int E, int chunk, int nbuckets) {
    __shared__ unsigned h[NBK];
    int bid = blockIdx.x, t = threadIdx.x, lane = t & 63, w = t >> 6;
    if (bid < NCH) {                    // hist-only blocks (uniform condition)
        int b = xcd_chunk(bid);         // swizzled chunk id (bijective on [0,NCH))
        for (int i = t; i < nbuckets; i += BT) h[i] = 0u;
        __syncthreads();
        int base = b * chunk, lim = min(base + chunk, E);
        int vbeg = (base + 3) & ~3; if (vbeg > lim) vbeg = lim;
        int vend = lim & ~3;        if (vend < vbeg) vend = vbeg;
        for (int e = base + t; e < vbeg; e += BT)
            atomicAdd(&h[((unsigned)ei[e]) >> BBITS], 1u);
        for (int i = vbeg + 4 * t; i < vend; i += 4 * BT) {
            int4 v4 = *(const int4*)(ei + i);
            atomicAdd(&h[((unsigned)v4.x) >> BBITS], 1u);
            atomicAdd(&h[((unsigned)v4.y) >> BBITS], 1u);
            atomicAdd(&h[((unsigned)v4.z) >> BBITS], 1u);
            atomicAdd(&h[((unsigned)v4.w) >> BBITS], 1u);
        }
        for (int e = vend + t; e < lim; e += BT)
            atomicAdd(&h[((unsigned)ei[e]) >> BBITS], 1u);
        __syncthreads();
        for (int v = t; v < nbuckets; v += BT) {
            unsigned c = h[v];
            hist[(size_t)v * NCH + b] = c;
            if (c) atomicAdd(&btot[v], c);   // bucket totals for free (was k_btot)
        }
    } else {
        // argmax blocks: 2 rows per wave (float4; half-waves of 32 lanes)
        int ab = bid - NCH;
        int half = lane >> 5, li = lane & 31;
        for (int pr = ab * MSDW + w; 2 * pr < N; pr += (GRID_F - NCH) * MSDW) {
            int r = 2 * pr + half;
            float bv = -3.4e38f; int bi = 0;
            if (r < N) {
                float4 v = ((const float4*)(x + (size_t)r * WL_D))[li];
                bv = v.x; bi = 4 * li;
                if (v.y > bv) { bv = v.y; bi = 4 * li + 1; }
                if (v.z > bv) { bv = v.z; bi = 4 * li + 2; }
                if (v.w > bv) { bv = v.w; bi = 4 * li + 3; }
            }
            #pragma unroll
            for (int off = 16; off > 0; off >>= 1) {
                float ov = __shfl_down(bv, off, 32);
                int   oi = __shfl_down(bi, off, 32);
                if (ov > bv || (ov == bv && oi < bi)) { bv = ov; bi = oi; }
            }
            if (li == 0 && r < N) lab0[r] = (unsigned)bi;
        }
    }
}

// ---- prep: bstart prefix (replicated) + in-wave chunk scan -> transposed histT ----
__global__ void __launch_bounds__(BT)
k_prep(const unsigned* __restrict__ hist, const unsigned* __restrict__ btot,
       unsigned* __restrict__ histT, unsigned* __restrict__ bstart,
       int nbuckets, int E) {
    __shared__ unsigned tile[NCH * 9];   // [512 chunks][8 waves], pad stride 9 (18 KB)
    __shared__ unsigned sS[MSDW];
    int t = threadIdx.x, w = t >> 6, lane = t & 63;
    int v = blockIdx.x * MSDW + w;
    bool act = (v < nbuckets);
    // bstart[v] = sum_{u<v} btot[u] (lane-parallel partial + butterfly)
    unsigned S = 0;
    if (act) for (int u = lane; u < v; u += 64) S += btot[u];
    #pragma unroll
    for (int o = 1; o < 64; o <<= 1) S += __shfl_xor(S, o, 64);
    if (lane == 0) { sS[w] = act ? S : 0u; if (act) bstart[v] = S; }
    if (blockIdx.x == 0 && t == 0) bstart[nbuckets] = (unsigned)E;
    // exclusive scan of the bucket's 512 chunk counts (in-wave, chunk order)
    unsigned carry = 0;
    #pragma unroll
    for (int j = 0; j < NCH / 64; ++j) {
        unsigned xv = act ? hist[(size_t)v * NCH + j * 64 + lane] : 0u;
        unsigned a = xv;
        #pragma unroll
        for (int o = 1; o < 64; o <<= 1) {
            unsigned u = __shfl_up(a, o, 64);
            if (lane >= o) a += u;
        }
        unsigned excl = a - xv + carry;
        carry += __shfl(a, 63, 64);
        tile[(j * 64 + lane) * 9 + w] = excl;
    }
    __syncthreads();
    // transposed write: histT[chunk][v] (consecutive threads -> contiguous v's)
    for (int i = t; i < NCH * MSDW; i += BT) {
        int c = i >> 3, w2 = i & 7;
        int v2 = blockIdx.x * MSDW + w2;
        if (v2 < nbuckets) histT[(size_t)c * nbuckets + v2] = tile[c * 9 + w2] + sS[w2];
    }
}

// ---- stable MSD scatter: prefetched batches, LDS cursors; 3 blocks/CU ----
__global__ void __launch_bounds__(BT, 6)
k_scatter(const int* __restrict__ ei, const unsigned* __restrict__ histT,
          unsigned* __restrict__ buf, int E, int chunk, int nbuckets) {
    __shared__ unsigned wbase[MSDW * NBK];   // 32 KB
    int b = xcd_chunk(blockIdx.x);           // swizzled chunk id
    int t = threadIdx.x, lane = t & 63, w = t >> 6;
    unsigned long long lmask = (1ull << lane) - 1ull;
    for (int i = t; i < MSDW * NBK; i += BT) wbase[i] = 0u;
    __syncthreads();
    int base = b * chunk, lim = min(base + chunk, E);
    int sub  = (chunk + MSDW - 1) / MSDW;
    int wbeg = base + w * sub;
    int wend = min(wbeg + sub, lim);
    int nbat = (wbeg < wend) ? ((wend - wbeg + 63) >> 6) : 0;
    // prefetch all row loads (static reg indices; issued before any ballot chain)
    unsigned r_[NBMAX];
    #pragma unroll
    for (int k = 0; k < NBMAX; ++k) {
        int e = wbeg + k * 64 + lane;
        r_[k] = (e < wend) ? (unsigned)ei[e] : 0u;
    }
    // pass A: per-wave bucket counts
    #pragma unroll
    for (int k = 0; k < NBMAX; ++k) {
        if (k >= nbat) break;
        int e = wbeg + k * 64 + lane;
        bool act = (e < wend);
        unsigned v = act ? (r_[k] >> BBITS) : (NBK - 1u);
        unsigned long long m = match_key<10>(v);
        unsigned before = (unsigned)__popcll(m & lmask);
        if (act && before == 0u) wbase[w * NBK + v] += (unsigned)__popcll(m);
    }
    for (int k = NBMAX; k < nbat; ++k) {     // dynamic tail (robustness)
        int e = wbeg + k * 64 + lane;
        bool act = (e < wend);
        unsigned v = act ? (((unsigned)ei[e]) >> BBITS) : (NBK - 1u);
        unsigned long long m = match_key<10>(v);
        unsigned before = (unsigned)__popcll(m & lmask);
        if (act && before == 0u) wbase[w * NBK + v] += (unsigned)__popcll(m);
    }
    __syncthreads();
    // seed per-wave cursors from transposed bases (coalesced)
    for (int v = t; v < nbuckets; v += BT) {
        unsigned g = histT[(size_t)b * nbuckets + v];
        #pragma unroll
        for (int w2 = 0; w2 < MSDW; ++w2) {
            unsigned cnt = wbase[w2 * NBK + v];
            wbase[w2 * NBK + v] = g;
            g += cnt;
        }
    }
    __syncthreads();
    // pass B: prefetch cols (rows still live in r_), recompute masks, stable scatter
    unsigned c_[NBMAX];
    #pragma unroll
    for (int k = 0; k < NBMAX; ++k) {
        int e = wbeg + k * 64 + lane;
        c_[k] = (e < wend) ? (unsigned)ei[(size_t)E + e] : 0u;
    }
    #pragma unroll
    for (int k = 0; k < NBMAX; ++k) {
        if (k >= nbat) break;
        int e = wbeg + k * 64 + lane;
        bool act = (e < wend);
        unsigned r = r_[k], col = c_[k];
        unsigned v = act ? (r >> BBITS) : (NBK - 1u);
        unsigned long long m = match_key<10>(v);
        unsigned before = (unsigned)__popcll(m & lmask);
        int leader = __ffsll(m) - 1;
        unsigned base0 = 0;
        if (act && before == 0u) {
            base0 = wbase[w * NBK + v];
            wbase[w * NBK + v] = base0 + (unsigned)__popcll(m);
        }
        base0 = __shfl(base0, leader, 64);
        if (act) buf[base0 + before] = ((r & (BROWS - 1u)) << RLSHIFT) | col;
    }
    for (int k = NBMAX; k < nbat; ++k) {     // dynamic tail
        int e = wbeg + k * 64 + lane;
        bool act = (e < wend);
        unsigned r   = act ? (unsigned)ei[e] : 0u;
        unsigned col = act ? (unsigned)ei[(size_t)E + e] : 0u;
        unsigned v = act ? (r >> BBITS) : (NBK - 1u);
        unsigned long long m = match_key<10>(v);
        unsigned before = (unsigned)__popcll(m & lmask);
        unsigned total  = (unsigned)__popcll(m);
        int leader = __ffsll(m) - 1;
        unsigned base0 = 0;
        if (act && before == 0u) { base0 = wbase[w * NBK + v]; wbase[w * NBK + v] = base0 + total; }
        base0 = __shfl(base0, leader, 64);
        if (act) buf[base0 + before] = ((r & (BROWS - 1u)) << RLSHIFT) | col;
    }
}

// ---- per-bucket stable counting sort by rl (reg-prefetched, LDS-staged out)
//      + FUSED first prop ----
__global__ void __launch_bounds__(BT)
k_bucket(const unsigned* __restrict__ buf, const unsigned* __restrict__ bstart,
         unsigned* __restrict__ csr, unsigned* __restrict__ rs_g,
         const unsigned* __restrict__ lab0, unsigned* __restrict__ lab1,
         int N, int E, int nbuckets) {
    __shared__ unsigned data2[CMAX];          // 20 KB (sorted output staging)
    __shared__ unsigned h2[MSDW * BROWS];     // 4 KB
    __shared__ unsigned offs[BROWS];          // 0.5 KB
    int bb = blockIdx.x, t = threadIdx.x, lane = t & 63, w = t >> 6;
    unsigned long long lmask = (1ull << lane) - 1ull;
    unsigned start = bstart[bb];
    unsigned end   = bstart[bb + 1];
    unsigned len = end - start;
    bool lds_ok = (len <= CMAX);
    for (int i = t; i < MSDW * BROWS; i += BT) h2[i] = 0u;
    __syncthreads();
    unsigned sub  = (len + MSDW - 1u) / MSDW;
    unsigned wbeg = w * sub;
    unsigned wend = min(wbeg + sub, len);
    int nbat = (wbeg < wend) ? (int)((wend - wbeg + 63u) >> 6) : 0;
    // prefetch the wave's whole slice into regs
    unsigned d_[KBMAX];
    #pragma unroll
    for (int k = 0; k < KBMAX; ++k) {
        unsigned i = wbeg + (unsigned)(k * 64 + lane);
        d_[k] = (i < wend) ? buf[start + i] : 0u;
    }
    // pass A: per-wave rl counts (ballots overlap the prefetch)
    #pragma unroll
    for (int k = 0; k < KBMAX; ++k) {
        if (k >= nbat) break;
        unsigned i = wbeg + (unsigned)(k * 64 + lane);
        bool act = (i < wend);
        unsigned v = act ? (d_[k] >> RLSHIFT) : 255u;
        unsigned long long m = match_key<8>(v);
        unsigned before = (unsigned)__popcll(m & lmask);
        unsigned total  = (unsigned)__popcll(m);
        if (act && before == 0u) h2[w * BROWS + v] += total;
    }
    for (int k = KBMAX; k < nbat; ++k) {     // dynamic tail (giant-bucket fallback)
        unsigned i = wbeg + (unsigned)(k * 64 + lane);
        bool act = (i < wend);
        unsigned v = act ? (buf[start + i] >> RLSHIFT) : 255u;
        unsigned long long m = match_key<8>(v);
        unsigned before = (unsigned)__popcll(m & lmask);
        unsigned total  = (unsigned)__popcll(m);
        if (act && before == 0u) h2[w * BROWS + v] += total;
    }
    __syncthreads();
    // per-row totals -> offs (inclusive scan via wave-0 shfl; 2 barriers not 16)
    unsigned hv = 0;
    if (t < BROWS) {
        #pragma unroll
        for (int w2 = 0; w2 < MSDW; ++w2) hv += h2[w2 * BROWS + t];
        offs[t] = hv;
    }
    __syncthreads();
    if (t < 64) {
        unsigned a = offs[t], b2 = offs[t + 64];
        #pragma unroll
        for (int o = 1; o < 64; o <<= 1) {
            unsigned ua = __shfl_up(a, o, 64);
            unsigned ub = __shfl_up(b2, o, 64);
            if (t >= o) { a += ua; b2 += ub; }
        }
        unsigned tot = __shfl(a, 63, 64);
        offs[t] = a;                     // inclusive over first 64 rows
        offs[t + 64] = b2 + tot;         // inclusive over all 128
    }
    __syncthreads();
    if (t < BROWS) {
        unsigned excl = offs[t] - hv;
        int row = bb * BROWS + t;
        if (row < N) rs_g[row] = start + excl;
        unsigned g = lds_ok ? excl : (start + excl);   // bucket-relative if LDS-staged
        #pragma unroll
        for (int w2 = 0; w2 < MSDW; ++w2) {
            unsigned cnt = h2[w2 * BROWS + t];
            h2[w2 * BROWS + t] = g;
            g += cnt;
        }
    }
    __syncthreads();
    // pass B: stable scatter cols (from regs) into LDS staging / csr fallback
    #pragma unroll
    for (int k = 0; k < KBMAX; ++k) {
        if (k >= nbat) break;
        unsigned i = wbeg + (unsigned)(k * 64 + lane);
        bool act = (i < wend);
        unsigned p = d_[k];
        unsigned v = act ? (p >> RLSHIFT) : 255u;
        unsigned long long m = match_key<8>(v);
        unsigned before = (unsigned)__popcll(m & lmask);
        unsigned total  = (unsigned)__popcll(m);
        int leader = __ffsll(m) - 1;
        unsigned base0 = 0;
        if (act && before == 0u) { base0 = h2[w * BROWS + v]; h2[w * BROWS + v] = base0 + total; }
        base0 = __shfl(base0, leader, 64);
        if (act) {
            if (lds_ok) data2[base0 + before] = p & COLMASK;
            else        csr[base0 + before]   = p & COLMASK;
        }
    }
    for (int k = KBMAX; k < nbat; ++k) {     // dynamic tail
        unsigned i = wbeg + (unsigned)(k * 64 + lane);
        bool act = (i < wend);
        unsigned p = act ? buf[start + i] : 0u;
        unsigned v = act ? (p >> RLSHIFT) : 255u;
        unsigned long long m = match_key<8>(v);
        unsigned before = (unsigned)__popcll(m & lmask);
        unsigned total  = (unsigned)__popcll(m);
        int leader = __ffsll(m) - 1;
        unsigned base0 = 0;
        if (act && before == 0u) { base0 = h2[w * BROWS + v]; h2[w * BROWS + v] = base0 + total; }
        base0 = __shfl(base0, leader, 64);
        if (act) {
            if (lds_ok) data2[base0 + before] = p & COLMASK;
            else        csr[base0 + before]   = p & COLMASK;
        }
    }
    __syncthreads();
    // stream sorted bucket out FIRST: the stores drain underneath the fused prop
    if (lds_ok) for (unsigned i = t; i < len; i += BT) csr[start + i] = data2[i];
    // FUSED first prop: lab1 for this bucket's rows, 8 lanes/row, cols from LDS.
    const unsigned H1 = HP8, H2 = HP8 * HP8, H3 = H2 * HP8, H4 = H3 * HP8;
    const unsigned* srcp = lds_ok ? (const unsigned*)data2 : (csr + start);
    int l = t & 7;
    for (int r0 = t >> 3; r0 < BROWS; r0 += BT / 8) {
        unsigned beg = r0 ? offs[r0 - 1] : 0u;
        unsigned d   = offs[r0] - beg;
        unsigned h = 0u;
        unsigned M = (d > (unsigned)l) ? ((d - (unsigned)l + 7u) >> 3) : 0u;
        unsigned bidx = beg + (unsigned)l;
        unsigned m = 0;
        for (; m + 4u <= M; m += 4u) {
            unsigned c0 = srcp[bidx + 8u * m];
            unsigned c1 = srcp[bidx + 8u * m + 8u];
            unsigned c2 = srcp[bidx + 8u * m + 16u];
            unsigned c3 = srcp[bidx + 8u * m + 24u];
            unsigned l0 = lab0[c0], l1 = lab0[c1], l2 = lab0[c2], l3 = lab0[c3];
            h = h * H4 + l0 * H3 + l1 * H2 + l2 * H1 + l3;
        }
        for (; m + 2u <= M; m += 2u) {
            unsigned c0 = srcp[bidx + 8u * m];
            unsigned c1 = srcp[bidx + 8u * m + 8u];
            h = h * H2 + lab0[c0] * H1 + lab0[c1];
        }
        for (; m < M; ++m) h = h * H1 + lab0[srcp[bidx + 8u * m]];
        if (M) {
            unsigned T = d - 1u - (unsigned)l - 8u * (M - 1u);   // in [0,7]
            unsigned p = ((T & 1u) ? 31u : 1u) * ((T & 2u) ? 961u : 1u)
                       * ((T & 4u) ? 923521u : 1u);
            h *= p;
        }
        h += __shfl_xor(h, 1, 64);
        h += __shfl_xor(h, 2, 64);
        h += __shfl_xor(h, 4, 64);
        int row = bb * BROWS + r0;
        if (l == 0 && row < N) lab1[row] = h;
    }
}

// ---- prop: 8 lanes per row, 4/2-wide reassociated base-31^8 Horner ----
__device__ inline unsigned horner8(const unsigned* __restrict__ csr,
                                   const unsigned* __restrict__ rs,
                                   const unsigned* __restrict__ lin,
                                   int g, int l, int N, int E) {
    const unsigned H1 = HP8, H2 = HP8 * HP8, H3 = H2 * HP8, H4 = H3 * HP8;
    unsigned s = rs[g];
    unsigned e = (g + 1 < N) ? rs[g + 1] : (unsigned)E;
    unsigned d = e - s;
    unsigned h = 0u;
    unsigned M = (d > (unsigned)l) ? ((d - (unsigned)l + 7u) >> 3) : 0u;
    unsigned bidx = s + (unsigned)l;
    unsigned m = 0;
    for (; m + 4u <= M; m += 4u) {
        unsigned c0 = csr[bidx + 8u * m];
        unsigned c1 = csr[bidx + 8u * m + 8u];
        unsigned c2 = csr[bidx + 8u * m + 16u];
        unsigned c3 = csr[bidx + 8u * m + 24u];
        unsigned l0 = lin[c0], l1 = lin[c1], l2 = lin[c2], l3 = lin[c3];
        h = h * H4 + l0 * H3 + l1 * H2 + l2 * H1 + l3;
    }
    for (; m + 2u <= M; m += 2u) {
        unsigned c0 = csr[bidx + 8u * m];
        unsigned c1 = csr[bidx + 8u * m + 8u];
        h = h * H2 + lin[c0] * H1 + lin[c1];
    }
    for (; m < M; ++m) h = h * H1 + lin[csr[bidx + 8u * m]];
    if (M) {
        unsigned T = d - 1u - (unsigned)l - 8u * (M - 1u);   // in [0,7]
        unsigned p = ((T & 1u) ? 31u : 1u) * ((T & 2u) ? 961u : 1u)
                   * ((T & 4u) ? 923521u : 1u);
        h *= p;
    }
    h += __shfl_xor(h, 1, 64);
    h += __shfl_xor(h, 2, 64);
    h += __shfl_xor(h, 4, 64);
    return h;
}

__global__ void __launch_bounds__(BT)
k_prop(const unsigned* __restrict__ csr, const unsigned* __restrict__ rs,
       const unsigned* __restrict__ lin, unsigned* __restrict__ lout,
       int N, int E) {
    int idx = blockIdx.x * BT + threadIdx.x;
    int g = idx >> 3, l = idx & 7;
    if (g >= N) return;
    unsigned h = horner8(csr, rs, lin, g, l, N, E);
    if (l == 0) lout[g] = h;
}

// final prop: writes lab3 straight into out[0..N) and out[4N..5N), plus copies
// lab0..2 into out[N..4N)
__global__ void __launch_bounds__(BT)
k_prop_final(const unsigned* __restrict__ csr, const unsigned* __restrict__ rs,
             const unsigned* __restrict__ lin, const unsigned* __restrict__ l0,
             const unsigned* __restrict__ l1, int* __restrict__ out,
             int N, int E, int pgrid) {
    int idx = blockIdx.x * BT + threadIdx.x;
    int g = idx >> 3, l = idx & 7;
    if (g < N) {
        unsigned h = horner8(csr, rs, lin, g, l, N, E);
        if (l == 0) { out[g] = (int)h; out[4 * N + g] = (int)h; }
    }
    for (int i = idx; i < N; i += pgrid * BT) {
        out[N + i]     = (int)l0[i];
        out[2 * N + i] = (int)l1[i];
        out[3 * N + i] = (int)lin[i];    // lin == lab2 on the final pass
    }
}

extern "C" void kernel_launch(void* const* d_in, const int* in_sizes, int n_in,
                              void* d_out, int out_size, void* d_ws, size_t ws_size,
                              hipStream_t stream) {
    const float* x  = (const float*)d_in[0];
    const int*   ei = (const int*)d_in[1];
    int* out = (int*)d_out;

    int N = in_sizes[0] / WL_D;
    int E = in_sizes[1] / 2;
    int chunk    = (E + NCH - 1) / NCH;        // 6250
    int nbuckets = (N + BROWS - 1) / BROWS;    // 782
    int L        = nbuckets * NCH;             // 400,384
    int pbk      = (nbuckets + MSDW - 1) / MSDW; // 98 (wave-per-bucket grid)
    int pgrid    = (8 * N + BT - 1) / BT;      // 1563 (8 lanes per row)

    // workspace layout (uint32 units) — everything written before read
    unsigned* ws    = (unsigned*)d_ws;
    unsigned* lab0  = ws;               // N
    unsigned* lab1  = lab0 + N;         // N
    unsigned* lab2  = lab1 + N;         // N
    unsigned* rs    = lab2 + N;         // N
    unsigned* btot  = rs + N;           // 1024 (nbuckets used; zeroed by memset)
    unsigned* bstart= btot + 1024;      // 1024 (nbuckets+1 used)
    unsigned* hist  = bstart + 1024;    // L (raw counts; never rewritten)
    unsigned* buf   = hist + L;         // E
    unsigned* csr   = buf + E;          // E
    unsigned* histT = csr;              // transient: csr space is free until k_bucket

    hipMemsetAsync(btot, 0, 1024 * sizeof(unsigned), stream);
    k_hist_argmax<<<GRID_F, BT, 0, stream>>>(x, ei, lab0, hist, btot, N, E, chunk, nbuckets);
    k_prep<<<pbk, BT, 0, stream>>>(hist, btot, histT, bstart, nbuckets, E);
    k_scatter<<<NCH, BT, 0, stream>>>(ei, histT, buf, E, chunk, nbuckets);
    k_bucket<<<nbuckets, BT, 0, stream>>>(buf, bstart, csr, rs, lab0, lab1, N, E, nbuckets);
    k_prop<<<pgrid, BT, 0, stream>>>(csr, rs, lab1, lab2, N, E);
    k_prop_final<<<pgrid, BT, 0, stream>>>(csr, rs, lab2, lab0, lab1, out, N, E, pgrid);
}

// Round 13
// 197.350 us; speedup vs baseline: 1.0437x; 1.0437x over previous
//
#include <hip/hip_runtime.h>
#include <hip/hip_bf16.h>

// WeisfeilerLehman: labels0 = argmax(x, -1); 3x ordered polynomial hash over edges.
// All arithmetic mod 2^32 (uint32 wrap) == reference int64 truncated to int32.
// R22/R23: prefix-path restructure (k_btot + k_prep replace scan+transp);
//      hist never rewritten. Measured 195.7us (session best).
// R24: k_btot folded into hist via hipMemsetAsync(btot) -- REGRESSED to 206us
//      (runtime fill inside kernel_launch enters the replay stream as an extra
//      dispatch costing ~10us). 
// R25: exact revert to the R23-measured kernel. No new changes.

#define WL_D 128
#define NCH 512             // MSD chunk count (scatter grid)
#define GRID_F 2048         // fused hist/argmax grid
#define BT 512              // threads per block (8 waves)
#define MSDW 8
#define BBITS 7             // bucket = row >> 7
#define BROWS 128           // rows per bucket
#define NBK 1024            // max buckets (N <= 131072)
#define RLSHIFT 23          // buf pack: (rl << 23) | col   (col < 2^23)
#define COLMASK ((1u << RLSHIFT) - 1u)
#define CMAX 5120           // LDS-staged output cap (20 KB)
#define NBMAX 13            // unrolled batches per wave in k_scatter (chunk 6250)
#define KBMAX 10            // unrolled batches per wave in k_bucket (len <= CMAX)
#define HP8 2487512833u     // 31^8 mod 2^32

// XCD-chunked chunk assignment: blockIdx -> chunk such that each XCD (bid % 8
// under round-robin dispatch) owns NCH/8 consecutive chunks. Bijective on [0,NCH).
__device__ inline int xcd_chunk(int bid) { return ((bid & 7) << 6) | (bid >> 3); }

// mask of lanes whose low BITS bits of v match mine (inactive lanes use a
// sentinel outside the valid key range so they never match active lanes)
template <int BITS>
__device__ inline unsigned long long match_key(unsigned v) {
    unsigned long long m = ~0ull;
    #pragma unroll
    for (int b = 0; b < BITS; ++b) {
        unsigned long long s = __ballot((v >> b) & 1u);
        m &= ((v >> b) & 1u) ? s : ~s;
    }
    return m;
}

// ---- fused: chunk bucket-histogram (blocks < NCH) OR argmax (blocks >= NCH) ----
__global__ void __launch_bounds__(BT)
k_hist_argmax(const float* __restrict__ x, const int* __restrict__ ei,
              unsigned* __restrict__ lab0, unsigned* __restrict__ hist,
              int N, int E, int chunk, int nbuckets) {
    __shared__ unsigned h[NBK];
    int bid = blockIdx.x, t = threadIdx.x, lane = t & 63, w = t >> 6;
    if (bid < NCH) {                    // hist-only blocks (uniform condition)
        int b = xcd_chunk(bid);         // swizzled chunk id (bijective on [0,NCH))
        for (int i = t; i < nbuckets; i += BT) h[i] = 0u;
        __syncthreads();
        int base = b * chunk, lim = min(base + chunk, E);
        int vbeg = (base + 3) & ~3; if (vbeg > lim) vbeg = lim;
        int vend = lim & ~3;        if (vend < vbeg) vend = vbeg;
        for (int e = base + t; e < vbeg; e += BT)
            atomicAdd(&h[((unsigned)ei[e]) >> BBITS], 1u);
        for (int i = vbeg + 4 * t; i < vend; i += 4 * BT) {
            int4 v4 = *(const int4*)(ei + i);
            atomicAdd(&h[((unsigned)v4.x) >> BBITS], 1u);
            atomicAdd(&h[((unsigned)v4.y) >> BBITS], 1u);
            atomicAdd(&h[((unsigned)v4.z) >> BBITS], 1u);
            atomicAdd(&h[((unsigned)v4.w) >> BBITS], 1u);
        }
        for (int e = vend + t; e < lim; e += BT)
            atomicAdd(&h[((unsigned)ei[e]) >> BBITS], 1u);
        __syncthreads();
        for (int v = t; v < nbuckets; v += BT) hist[(size_t)v * NCH + b] = h[v];
    } else {
        // argmax blocks: 2 rows per wave (float4; half-waves of 32 lanes)
        int ab = bid - NCH;
        int half = lane >> 5, li = lane & 31;
        for (int pr = ab * MSDW + w; 2 * pr < N; pr += (GRID_F - NCH) * MSDW) {
            int r = 2 * pr + half;
            float bv = -3.4e38f; int bi = 0;
            if (r < N) {
                float4 v = ((const float4*)(x + (size_t)r * WL_D))[li];
                bv = v.x; bi = 4 * li;
                if (v.y > bv) { bv = v.y; bi = 4 * li + 1; }
                if (v.z > bv) { bv = v.z; bi = 4 * li + 2; }
                if (v.w > bv) { bv = v.w; bi = 4 * li + 3; }
            }
            #pragma unroll
            for (int off = 16; off > 0; off >>= 1) {
                float ov = __shfl_down(bv, off, 32);
                int   oi = __shfl_down(bi, off, 32);
                if (ov > bv || (ov == bv && oi < bi)) { bv = ov; bi = oi; }
            }
            if (li == 0 && r < N) lab0[r] = (unsigned)bi;
        }
    }
}

// ---- per-bucket totals: one wave per bucket, 8 coalesced loads + butterfly ----
__global__ void __launch_bounds__(BT)
k_btot(const unsigned* __restrict__ hist, unsigned* __restrict__ btot,
       int nbuckets) {
    int t = threadIdx.x, w = t >> 6, lane = t & 63;
    int v = blockIdx.x * MSDW + w;
    if (v >= nbuckets) return;          // whole wave exits; no barriers below
    unsigned s = 0;
    #pragma unroll
    for (int j = 0; j < NCH / 64; ++j) s += hist[(size_t)v * NCH + j * 64 + lane];
    #pragma unroll
    for (int o = 1; o < 64; o <<= 1) s += __shfl_xor(s, o, 64);
    if (lane == 0) btot[v] = s;
}

// ---- prep: bstart prefix (replicated) + in-wave chunk scan -> transposed histT ----
__global__ void __launch_bounds__(BT)
k_prep(const unsigned* __restrict__ hist, const unsigned* __restrict__ btot,
       unsigned* __restrict__ histT, unsigned* __restrict__ bstart,
       int nbuckets, int E) {
    __shared__ unsigned tile[NCH * 9];   // [512 chunks][8 waves], pad stride 9 (18 KB)
    __shared__ unsigned sS[MSDW];
    int t = threadIdx.x, w = t >> 6, lane = t & 63;
    int v = blockIdx.x * MSDW + w;
    bool act = (v < nbuckets);
    // bstart[v] = sum_{u<v} btot[u] (lane-parallel partial + butterfly)
    unsigned S = 0;
    if (act) for (int u = lane; u < v; u += 64) S += btot[u];
    #pragma unroll
    for (int o = 1; o < 64; o <<= 1) S += __shfl_xor(S, o, 64);
    if (lane == 0) { sS[w] = act ? S : 0u; if (act) bstart[v] = S; }
    if (blockIdx.x == 0 && t == 0) bstart[nbuckets] = (unsigned)E;
    // exclusive scan of the bucket's 512 chunk counts (in-wave, chunk order)
    unsigned carry = 0;
    #pragma unroll
    for (int j = 0; j < NCH / 64; ++j) {
        unsigned xv = act ? hist[(size_t)v * NCH + j * 64 + lane] : 0u;
        unsigned a = xv;
        #pragma unroll
        for (int o = 1; o < 64; o <<= 1) {
            unsigned u = __shfl_up(a, o, 64);
            if (lane >= o) a += u;
        }
        unsigned excl = a - xv + carry;
        carry += __shfl(a, 63, 64);
        tile[(j * 64 + lane) * 9 + w] = excl;
    }
    __syncthreads();
    // transposed write: histT[chunk][v] (consecutive threads -> contiguous v's)
    for (int i = t; i < NCH * MSDW; i += BT) {
        int c = i >> 3, w2 = i & 7;
        int v2 = blockIdx.x * MSDW + w2;
        if (v2 < nbuckets) histT[(size_t)c * nbuckets + v2] = tile[c * 9 + w2] + sS[w2];
    }
}

// ---- stable MSD scatter: prefetched batches, LDS cursors; 3 blocks/CU ----
__global__ void __launch_bounds__(BT, 6)
k_scatter(const int* __restrict__ ei, const unsigned* __restrict__ histT,
          unsigned* __restrict__ buf, int E, int chunk, int nbuckets) {
    __shared__ unsigned wbase[MSDW * NBK];   // 32 KB
    int b = xcd_chunk(blockIdx.x);           // swizzled chunk id
    int t = threadIdx.x, lane = t & 63, w = t >> 6;
    unsigned long long lmask = (1ull << lane) - 1ull;
    for (int i = t; i < MSDW * NBK; i += BT) wbase[i] = 0u;
    __syncthreads();
    int base = b * chunk, lim = min(base + chunk, E);
    int sub  = (chunk + MSDW - 1) / MSDW;
    int wbeg = base + w * sub;
    int wend = min(wbeg + sub, lim);
    int nbat = (wbeg < wend) ? ((wend - wbeg + 63) >> 6) : 0;
    // prefetch all row loads (static reg indices; issued before any ballot chain)
    unsigned r_[NBMAX];
    #pragma unroll
    for (int k = 0; k < NBMAX; ++k) {
        int e = wbeg + k * 64 + lane;
        r_[k] = (e < wend) ? (unsigned)ei[e] : 0u;
    }
    // pass A: per-wave bucket counts
    #pragma unroll
    for (int k = 0; k < NBMAX; ++k) {
        if (k >= nbat) break;
        int e = wbeg + k * 64 + lane;
        bool act = (e < wend);
        unsigned v = act ? (r_[k] >> BBITS) : (NBK - 1u);
        unsigned long long m = match_key<10>(v);
        unsigned before = (unsigned)__popcll(m & lmask);
        if (act && before == 0u) wbase[w * NBK + v] += (unsigned)__popcll(m);
    }
    for (int k = NBMAX; k < nbat; ++k) {     // dynamic tail (robustness)
        int e = wbeg + k * 64 + lane;
        bool act = (e < wend);
        unsigned v = act ? (((unsigned)ei[e]) >> BBITS) : (NBK - 1u);
        unsigned long long m = match_key<10>(v);
        unsigned before = (unsigned)__popcll(m & lmask);
        if (act && before == 0u) wbase[w * NBK + v] += (unsigned)__popcll(m);
    }
    __syncthreads();
    // seed per-wave cursors from transposed bases (coalesced)
    for (int v = t; v < nbuckets; v += BT) {
        unsigned g = histT[(size_t)b * nbuckets + v];
        #pragma unroll
        for (int w2 = 0; w2 < MSDW; ++w2) {
            unsigned cnt = wbase[w2 * NBK + v];
            wbase[w2 * NBK + v] = g;
            g += cnt;
        }
    }
    __syncthreads();
    // pass B: prefetch cols (rows still live in r_), recompute masks, stable scatter
    unsigned c_[NBMAX];
    #pragma unroll
    for (int k = 0; k < NBMAX; ++k) {
        int e = wbeg + k * 64 + lane;
        c_[k] = (e < wend) ? (unsigned)ei[(size_t)E + e] : 0u;
    }
    #pragma unroll
    for (int k = 0; k < NBMAX; ++k) {
        if (k >= nbat) break;
        int e = wbeg + k * 64 + lane;
        bool act = (e < wend);
        unsigned r = r_[k], col = c_[k];
        unsigned v = act ? (r >> BBITS) : (NBK - 1u);
        unsigned long long m = match_key<10>(v);
        unsigned before = (unsigned)__popcll(m & lmask);
        int leader = __ffsll(m) - 1;
        unsigned base0 = 0;
        if (act && before == 0u) {
            base0 = wbase[w * NBK + v];
            wbase[w * NBK + v] = base0 + (unsigned)__popcll(m);
        }
        base0 = __shfl(base0, leader, 64);
        if (act) buf[base0 + before] = ((r & (BROWS - 1u)) << RLSHIFT) | col;
    }
    for (int k = NBMAX; k < nbat; ++k) {     // dynamic tail
        int e = wbeg + k * 64 + lane;
        bool act = (e < wend);
        unsigned r   = act ? (unsigned)ei[e] : 0u;
        unsigned col = act ? (unsigned)ei[(size_t)E + e] : 0u;
        unsigned v = act ? (r >> BBITS) : (NBK - 1u);
        unsigned long long m = match_key<10>(v);
        unsigned before = (unsigned)__popcll(m & lmask);
        unsigned total  = (unsigned)__popcll(m);
        int leader = __ffsll(m) - 1;
        unsigned base0 = 0;
        if (act && before == 0u) { base0 = wbase[w * NBK + v]; wbase[w * NBK + v] = base0 + total; }
        base0 = __shfl(base0, leader, 64);
        if (act) buf[base0 + before] = ((r & (BROWS - 1u)) << RLSHIFT) | col;
    }
}

// ---- per-bucket stable counting sort by rl (reg-prefetched, LDS-staged out)
//      + FUSED first prop ----
__global__ void __launch_bounds__(BT)
k_bucket(const unsigned* __restrict__ buf, const unsigned* __restrict__ bstart,
         unsigned* __restrict__ csr, unsigned* __restrict__ rs_g,
         const unsigned* __restrict__ lab0, unsigned* __restrict__ lab1,
         int N, int E, int nbuckets) {
    __shared__ unsigned data2[CMAX];          // 20 KB (sorted output staging)
    __shared__ unsigned h2[MSDW * BROWS];     // 4 KB
    __shared__ unsigned offs[BROWS];          // 0.5 KB
    int bb = blockIdx.x, t = threadIdx.x, lane = t & 63, w = t >> 6;
    unsigned long long lmask = (1ull << lane) - 1ull;
    unsigned start = bstart[bb];
    unsigned end   = bstart[bb + 1];
    unsigned len = end - start;
    bool lds_ok = (len <= CMAX);
    for (int i = t; i < MSDW * BROWS; i += BT) h2[i] = 0u;
    __syncthreads();
    unsigned sub  = (len + MSDW - 1u) / MSDW;
    unsigned wbeg = w * sub;
    unsigned wend = min(wbeg + sub, len);
    int nbat = (wbeg < wend) ? (int)((wend - wbeg + 63u) >> 6) : 0;
    // prefetch the wave's whole slice into regs
    unsigned d_[KBMAX];
    #pragma unroll
    for (int k = 0; k < KBMAX; ++k) {
        unsigned i = wbeg + (unsigned)(k * 64 + lane);
        d_[k] = (i < wend) ? buf[start + i] : 0u;
    }
    // pass A: per-wave rl counts (ballots overlap the prefetch)
    #pragma unroll
    for (int k = 0; k < KBMAX; ++k) {
        if (k >= nbat) break;
        unsigned i = wbeg + (unsigned)(k * 64 + lane);
        bool act = (i < wend);
        unsigned v = act ? (d_[k] >> RLSHIFT) : 255u;
        unsigned long long m = match_key<8>(v);
        unsigned before = (unsigned)__popcll(m & lmask);
        unsigned total  = (unsigned)__popcll(m);
        if (act && before == 0u) h2[w * BROWS + v] += total;
    }
    for (int k = KBMAX; k < nbat; ++k) {     // dynamic tail (giant-bucket fallback)
        unsigned i = wbeg + (unsigned)(k * 64 + lane);
        bool act = (i < wend);
        unsigned v = act ? (buf[start + i] >> RLSHIFT) : 255u;
        unsigned long long m = match_key<8>(v);
        unsigned before = (unsigned)__popcll(m & lmask);
        unsigned total  = (unsigned)__popcll(m);
        if (act && before == 0u) h2[w * BROWS + v] += total;
    }
    __syncthreads();
    // per-row totals -> offs (inclusive scan via wave-0 shfl; 2 barriers not 16)
    unsigned hv = 0;
    if (t < BROWS) {
        #pragma unroll
        for (int w2 = 0; w2 < MSDW; ++w2) hv += h2[w2 * BROWS + t];
        offs[t] = hv;
    }
    __syncthreads();
    if (t < 64) {
        unsigned a = offs[t], b2 = offs[t + 64];
        #pragma unroll
        for (int o = 1; o < 64; o <<= 1) {
            unsigned ua = __shfl_up(a, o, 64);
            unsigned ub = __shfl_up(b2, o, 64);
            if (t >= o) { a += ua; b2 += ub; }
        }
        unsigned tot = __shfl(a, 63, 64);
        offs[t] = a;                     // inclusive over first 64 rows
        offs[t + 64] = b2 + tot;         // inclusive over all 128
    }
    __syncthreads();
    if (t < BROWS) {
        unsigned excl = offs[t] - hv;
        int row = bb * BROWS + t;
        if (row < N) rs_g[row] = start + excl;
        unsigned g = lds_ok ? excl : (start + excl);   // bucket-relative if LDS-staged
        #pragma unroll
        for (int w2 = 0; w2 < MSDW; ++w2) {
            unsigned cnt = h2[w2 * BROWS + t];
            h2[w2 * BROWS + t] = g;
            g += cnt;
        }
    }
    __syncthreads();
    // pass B: stable scatter cols (from regs) into LDS staging / csr fallback
    #pragma unroll
    for (int k = 0; k < KBMAX; ++k) {
        if (k >= nbat) break;
        unsigned i = wbeg + (unsigned)(k * 64 + lane);
        bool act = (i < wend);
        unsigned p = d_[k];
        unsigned v = act ? (p >> RLSHIFT) : 255u;
        unsigned long long m = match_key<8>(v);
        unsigned before = (unsigned)__popcll(m & lmask);
        unsigned total  = (unsigned)__popcll(m);
        int leader = __ffsll(m) - 1;
        unsigned base0 = 0;
        if (act && before == 0u) { base0 = h2[w * BROWS + v]; h2[w * BROWS + v] = base0 + total; }
        base0 = __shfl(base0, leader, 64);
        if (act) {
            if (lds_ok) data2[base0 + before] = p & COLMASK;
            else        csr[base0 + before]   = p & COLMASK;
        }
    }
    for (int k = KBMAX; k < nbat; ++k) {     // dynamic tail
        unsigned i = wbeg + (unsigned)(k * 64 + lane);
        bool act = (i < wend);
        unsigned p = act ? buf[start + i] : 0u;
        unsigned v = act ? (p >> RLSHIFT) : 255u;
        unsigned long long m = match_key<8>(v);
        unsigned before = (unsigned)__popcll(m & lmask);
        unsigned total  = (unsigned)__popcll(m);
        int leader = __ffsll(m) - 1;
        unsigned base0 = 0;
        if (act && before == 0u) { base0 = h2[w * BROWS + v]; h2[w * BROWS + v] = base0 + total; }
        base0 = __shfl(base0, leader, 64);
        if (act) {
            if (lds_ok) data2[base0 + before] = p & COLMASK;
            else        csr[base0 + before]   = p & COLMASK;
        }
    }
    __syncthreads();
    // stream sorted bucket out FIRST: the stores drain underneath the fused prop
    if (lds_ok) for (unsigned i = t; i < len; i += BT) csr[start + i] = data2[i];
    // FUSED first prop: lab1 for this bucket's rows, 8 lanes/row, cols from LDS.
    const unsigned H1 = HP8, H2 = HP8 * HP8, H3 = H2 * HP8, H4 = H3 * HP8;
    const unsigned* srcp = lds_ok ? (const unsigned*)data2 : (csr + start);
    int l = t & 7;
    for (int r0 = t >> 3; r0 < BROWS; r0 += BT / 8) {
        unsigned beg = r0 ? offs[r0 - 1] : 0u;
        unsigned d   = offs[r0] - beg;
        unsigned h = 0u;
        unsigned M = (d > (unsigned)l) ? ((d - (unsigned)l + 7u) >> 3) : 0u;
        unsigned bidx = beg + (unsigned)l;
        unsigned m = 0;
        for (; m + 4u <= M; m += 4u) {
            unsigned c0 = srcp[bidx + 8u * m];
            unsigned c1 = srcp[bidx + 8u * m + 8u];
            unsigned c2 = srcp[bidx + 8u * m + 16u];
            unsigned c3 = srcp[bidx + 8u * m + 24u];
            unsigned l0 = lab0[c0], l1 = lab0[c1], l2 = lab0[c2], l3 = lab0[c3];
            h = h * H4 + l0 * H3 + l1 * H2 + l2 * H1 + l3;
        }
        for (; m + 2u <= M; m += 2u) {
            unsigned c0 = srcp[bidx + 8u * m];
            unsigned c1 = srcp[bidx + 8u * m + 8u];
            h = h * H2 + lab0[c0] * H1 + lab0[c1];
        }
        for (; m < M; ++m) h = h * H1 + lab0[srcp[bidx + 8u * m]];
        if (M) {
            unsigned T = d - 1u - (unsigned)l - 8u * (M - 1u);   // in [0,7]
            unsigned p = ((T & 1u) ? 31u : 1u) * ((T & 2u) ? 961u : 1u)
                       * ((T & 4u) ? 923521u : 1u);
            h *= p;
        }
        h += __shfl_xor(h, 1, 64);
        h += __shfl_xor(h, 2, 64);
        h += __shfl_xor(h, 4, 64);
        int row = bb * BROWS + r0;
        if (l == 0 && row < N) lab1[row] = h;
    }
}

// ---- prop: 8 lanes per row, 4/2-wide reassociated base-31^8 Horner ----
__device__ inline unsigned horner8(const unsigned* __restrict__ csr,
                                   const unsigned* __restrict__ rs,
                                   const unsigned* __restrict__ lin,
                                   int g, int l, int N, int E) {
    const unsigned H1 = HP8, H2 = HP8 * HP8, H3 = H2 * HP8, H4 = H3 * HP8;
    unsigned s = rs[g];
    unsigned e = (g + 1 < N) ? rs[g + 1] : (unsigned)E;
    unsigned d = e - s;
    unsigned h = 0u;
    unsigned M = (d > (unsigned)l) ? ((d - (unsigned)l + 7u) >> 3) : 0u;
    unsigned bidx = s + (unsigned)l;
    unsigned m = 0;
    for (; m + 4u <= M; m += 4u) {
        unsigned c0 = csr[bidx + 8u * m];
        unsigned c1 = csr[bidx + 8u * m + 8u];
        unsigned c2 = csr[bidx + 8u * m + 16u];
        unsigned c3 = csr[bidx + 8u * m + 24u];
        unsigned l0 = lin[c0], l1 = lin[c1], l2 = lin[c2], l3 = lin[c3];
        h = h * H4 + l0 * H3 + l1 * H2 + l2 * H1 + l3;
    }
    for (; m + 2u <= M; m += 2u) {
        unsigned c0 = csr[bidx + 8u * m];
        unsigned c1 = csr[bidx + 8u * m + 8u];
        h = h * H2 + lin[c0] * H1 + lin[c1];
    }
    for (; m < M; ++m) h = h * H1 + lin[csr[bidx + 8u * m]];
    if (M) {
        unsigned T = d - 1u - (unsigned)l - 8u * (M - 1u);   // in [0,7]
        unsigned p = ((T & 1u) ? 31u : 1u) * ((T & 2u) ? 961u : 1u)
                   * ((T & 4u) ? 923521u : 1u);
        h *= p;
    }
    h += __shfl_xor(h, 1, 64);
    h += __shfl_xor(h, 2, 64);
    h += __shfl_xor(h, 4, 64);
    return h;
}

__global__ void __launch_bounds__(BT)
k_prop(const unsigned* __restrict__ csr, const unsigned* __restrict__ rs,
       const unsigned* __restrict__ lin, unsigned* __restrict__ lout,
       int N, int E) {
    int idx = blockIdx.x * BT + threadIdx.x;
    int g = idx >> 3, l = idx & 7;
    if (g >= N) return;
    unsigned h = horner8(csr, rs, lin, g, l, N, E);
    if (l == 0) lout[g] = h;
}

// final prop: writes lab3 straight into out[0..N) and out[4N..5N), plus copies
// lab0..2 into out[N..4N)
__global__ void __launch_bounds__(BT)
k_prop_final(const unsigned* __restrict__ csr, const unsigned* __restrict__ rs,
             const unsigned* __restrict__ lin, const unsigned* __restrict__ l0,
             const unsigned* __restrict__ l1, int* __restrict__ out,
             int N, int E, int pgrid) {
    int idx = blockIdx.x * BT + threadIdx.x;
    int g = idx >> 3, l = idx & 7;
    if (g < N) {
        unsigned h = horner8(csr, rs, lin, g, l, N, E);
        if (l == 0) { out[g] = (int)h; out[4 * N + g] = (int)h; }
    }
    for (int i = idx; i < N; i += pgrid * BT) {
        out[N + i]     = (int)l0[i];
        out[2 * N + i] = (int)l1[i];
        out[3 * N + i] = (int)lin[i];    // lin == lab2 on the final pass
    }
}

extern "C" void kernel_launch(void* const* d_in, const int* in_sizes, int n_in,
                              void* d_out, int out_size, void* d_ws, size_t ws_size,
                              hipStream_t stream) {
    const float* x  = (const float*)d_in[0];
    const int*   ei = (const int*)d_in[1];
    int* out = (int*)d_out;

    int N = in_sizes[0] / WL_D;
    int E = in_sizes[1] / 2;
    int chunk    = (E + NCH - 1) / NCH;        // 6250
    int nbuckets = (N + BROWS - 1) / BROWS;    // 782
    int L        = nbuckets * NCH;             // 400,384
    int pbk      = (nbuckets + MSDW - 1) / MSDW; // 98 (wave-per-bucket grids)
    int pgrid    = (8 * N + BT - 1) / BT;      // 1563 (8 lanes per row)

    // workspace layout (uint32 units) — everything written before read
    unsigned* ws    = (unsigned*)d_ws;
    unsigned* lab0  = ws;               // N
    unsigned* lab1  = lab0 + N;         // N
    unsigned* lab2  = lab1 + N;         // N
    unsigned* rs    = lab2 + N;         // N
    unsigned* btot  = rs + N;           // 1024 (nbuckets used)
    unsigned* bstart= btot + 1024;      // 1024 (nbuckets+1 used)
    unsigned* hist  = bstart + 1024;    // L (raw counts; never rewritten)
    unsigned* buf   = hist + L;         // E
    unsigned* csr   = buf + E;          // E
    unsigned* histT = csr;              // transient: csr space is free until k_bucket

    k_hist_argmax<<<GRID_F, BT, 0, stream>>>(x, ei, lab0, hist, N, E, chunk, nbuckets);
    k_btot<<<pbk, BT, 0, stream>>>(hist, btot, nbuckets);
    k_prep<<<pbk, BT, 0, stream>>>(hist, btot, histT, bstart, nbuckets, E);
    k_scatter<<<NCH, BT, 0, stream>>>(ei, histT, buf, E, chunk, nbuckets);
    k_bucket<<<nbuckets, BT, 0, stream>>>(buf, bstart, csr, rs, lab0, lab1, N, E, nbuckets);
    k_prop<<<pgrid, BT, 0, stream>>>(csr, rs, lab1, lab2, N, E);
    k_prop_final<<<pgrid, BT, 0, stream>>>(csr, rs, lab2, lab0, lab1, out, N, E, pgrid);
}